// Round 5
// baseline (345.686 us; speedup 1.0000x reference)
//
#include <hip/hip_runtime.h>
#include <hip/hip_bf16.h>

typedef __hip_bfloat16 bf16;
typedef __attribute__((ext_vector_type(8))) __bf16 bf16x8;
typedef __attribute__((ext_vector_type(4))) float f32x4;

#define MFMA16(a, b, c) __builtin_amdgcn_mfma_f32_16x16x32_bf16((a), (b), (c), 0, 0, 0)

#define BT 4096      // B*T rows
#define CE 2048      // embed dim
#define NQKV 3072    // q(2048) + k(512) + v(512)
#define TSEQ 2048
#define HD 128

// q pre-scale: 1/sqrt(128) * log2(e), folded into rope_rms's q output.
#define QSCALE (0.08838834764831845f * 1.4426950408889634f)
// fixed softmax max bound: ||q'||*||k|| = 128*QSCALE (Cauchy-Schwarz on
// RMS-normalized vectors). p = 2^(s' - M2) <= ~1, no online max needed.
#define M2 16.3222f

// ---------------------------------------------------------------------------
// async global->LDS 16B copy (one instruction, no VGPR round trip)
__device__ __forceinline__ void gld16(const void* g, void* l)
{
    __builtin_amdgcn_global_load_lds(
        (const __attribute__((address_space(1))) void*)g,
        (__attribute__((address_space(3))) void*)l, 16, 0, 0);
}

// ---------------------------------------------------------------------------
// Input-dtype detector (inputs are fp32; gate kept for safety).
__global__ void detect_dtype(const unsigned short* __restrict__ x, int* __restrict__ flag)
{
    __shared__ int cnt;
    if (threadIdx.x == 0) cnt = 0;
    __syncthreads();
    unsigned short w = x[2 * threadIdx.x];
    int e = (w >> 7) & 0xFF;
    atomicAdd(&cnt, (e >= 117 && e <= 130) ? 1 : 0);
    __syncthreads();
    if (threadIdx.x == 0) *flag = (cnt < 128) ? 1 : 0;
}

// Stage 8 elems (16B bf16) into LDS from bf16 or fp32 source (VGPR convert).
__device__ __forceinline__ void stage8(short* dst, const void* src, size_t eoff, bool f32)
{
    if (f32) {
        const float* s = (const float*)src + eoff;
        float4 f0 = *(const float4*)s;
        float4 f1 = *(const float4*)(s + 4);
        bf16x8 v;
        v[0] = (__bf16)f0.x; v[1] = (__bf16)f0.y; v[2] = (__bf16)f0.z; v[3] = (__bf16)f0.w;
        v[4] = (__bf16)f1.x; v[5] = (__bf16)f1.y; v[6] = (__bf16)f1.z; v[7] = (__bf16)f1.w;
        *(bf16x8*)dst = v;
    } else {
        *(uint4*)dst = *(const uint4*)((const bf16*)src + eoff);
    }
}

__device__ __forceinline__ float ldf(const void* p, int i, bool f32)
{
    return f32 ? ((const float*)p)[i] : __bfloat162float(((const bf16*)p)[i]);
}

// ---------------------------------------------------------------------------
// fp32 (or bf16) -> bf16 conversion, 8 elems/thread.
__global__ __launch_bounds__(256)
void conv_bf16(const void* __restrict__ src, bf16* __restrict__ dst,
               const int* __restrict__ flagp)
{
    const bool f = *flagp != 0;
    size_t i8 = (size_t)blockIdx.x * 256 + threadIdx.x;
    stage8((short*)(dst + i8 * 8), src, i8 * 8, f);
}

// ---------------------------------------------------------------------------
// Legacy 128^2 GEMM, kept ONLY as ws-constrained fallback (fp32-A staging).
__global__ __launch_bounds__(256)
void gemm_bt(const void* __restrict__ A, const bf16* __restrict__ W,
             void* __restrict__ C, int M, int N, int K, int lda,
             int aGate, int oGate, const int* __restrict__ flagp)
{
    __shared__ short As[128][32];
    __shared__ short Bs[128][32];

    const int f = *flagp;
    const bool aF = aGate && f, oF = oGate && f;

    const int tid   = threadIdx.x;
    const int lane  = tid & 63;
    const int wid   = tid >> 6;
    const int row16 = lane & 15;
    const int quad  = lane >> 4;
    const int wr    = wid >> 1;
    const int wc    = wid & 1;
    const int m0    = blockIdx.y * 128;
    const int n0    = blockIdx.x * 128;

    const int rl4 = wid * 16 + (lane >> 2);
    const int c8  = (lane & 3) * 8;

    f32x4 acc[4][4];
#pragma unroll
    for (int i = 0; i < 4; i++)
#pragma unroll
        for (int j = 0; j < 4; j++)
            acc[i][j] = (f32x4){0.f, 0.f, 0.f, 0.f};

    for (int k0 = 0; k0 < K; k0 += 32) {
#pragma unroll
        for (int i = 0; i < 2; i++) {
            int r = i * 64 + rl4;
            gld16(W + (size_t)(n0 + r) * K + k0 + c8, &Bs[r][c8]);
        }
        if (!aF) {
#pragma unroll
            for (int i = 0; i < 2; i++) {
                int r = i * 64 + rl4;
                gld16((const bf16*)A + (size_t)(m0 + r) * lda + k0 + c8, &As[r][c8]);
            }
        } else {
#pragma unroll
            for (int i = 0; i < 2; i++) {
                int c = i * 256 + tid;
                int row = c >> 2, col = (c & 3) << 3;
                stage8(&As[row][col], A, (size_t)(m0 + row) * lda + k0 + col, true);
            }
        }
        __syncthreads();

        bf16x8 af[4], bfv[4];
#pragma unroll
        for (int mi = 0; mi < 4; mi++)
            af[mi] = *(const bf16x8*)&As[wr * 64 + mi * 16 + row16][quad * 8];
#pragma unroll
        for (int ni = 0; ni < 4; ni++)
            bfv[ni] = *(const bf16x8*)&Bs[wc * 64 + ni * 16 + row16][quad * 8];
#pragma unroll
        for (int mi = 0; mi < 4; mi++)
#pragma unroll
            for (int ni = 0; ni < 4; ni++)
                acc[mi][ni] = MFMA16(af[mi], bfv[ni], acc[mi][ni]);
        __syncthreads();
    }

#pragma unroll
    for (int mi = 0; mi < 4; mi++) {
        int rowb = m0 + wr * 64 + mi * 16 + quad * 4;
#pragma unroll
        for (int ni = 0; ni < 4; ni++) {
            int col = n0 + wc * 64 + ni * 16 + row16;
#pragma unroll
            for (int r = 0; r < 4; r++) {
                size_t idx = (size_t)(rowb + r) * N + col;
                float  v   = acc[mi][ni][r];
                if (oF) ((float*)C)[idx] = v;
                else    ((bf16*)C)[idx]  = __float2bfloat16(v);
            }
        }
    }
}

// ---------------------------------------------------------------------------
// R11 GEMM (unchanged from R4, verified): BM=MI*32 x BN=256, BK=64, 512 thr /
// 8 waves, double-buffered LDS, one vmcnt(0)+barrier per 64-K window,
// full-row XOR swizzle staged via pre-swizzled global source.
template<int MI>
__global__ __launch_bounds__(512, 2)
void gemmP(const bf16* __restrict__ A, const bf16* __restrict__ W,
           void* __restrict__ C, int M, int N, int K, int lda,
           int oGate, const int* __restrict__ flagp)
{
    constexpr int BM     = MI * 32;
    constexpr int ABYTES = BM * 128;        // bytes per A K-tile (BK=64 bf16)
    constexpr int AUL    = ABYTES / 8192;   // gld16 per thread for A (4 or 2)

    __shared__ __bf16 As[2][BM][64];
    __shared__ __bf16 Bs[2][256][64];

    const bool oF = oGate && (*flagp != 0);

    const int tid   = threadIdx.x;
    const int lane  = tid & 63;
    const int wid   = tid >> 6;
    const int row16 = lane & 15;
    const int quad  = lane >> 4;
    const int wr    = wid >> 2;          // 0..1
    const int wc    = wid & 3;           // 0..3
    const int m0    = blockIdx.y * BM;
    const int n0    = blockIdx.x * 256;
    const int NT    = K >> 6;            // 64-wide K-tiles

    const int srow = tid >> 3;                        // 0..63
    const int sc8  = ((tid & 7) ^ (srow & 7)) * 8;    // element offset
    const bf16* Ag = A + (size_t)(m0 + srow) * lda + sc8;
    const bf16* Bg = W + (size_t)(n0 + srow) * K   + sc8;
    char* const AsB = (char*)As;
    char* const BsB = (char*)Bs;
    const int sdst = tid * 16;

    auto stA = [&](int kt, int b) {
#pragma unroll
        for (int u = 0; u < AUL; ++u)
            gld16(Ag + (size_t)(u * 64) * lda + kt * 64,
                  AsB + b * ABYTES + u * 8192 + sdst);
    };
    auto stB = [&](int kt, int b) {
#pragma unroll
        for (int u = 0; u < 4; ++u)
            gld16(Bg + (size_t)(u * 64) * K + kt * 64,
                  BsB + b * 32768 + u * 8192 + sdst);
    };

    const int swz  = ((quad ^ (row16 & 7)) * 16);          // kk=0
    const int swz1 = (((4 + quad) ^ (row16 & 7)) * 16);    // kk=1
    const int aRow = wr * (MI * 16) + row16;
    const int bRow = wc * 64 + row16;

    auto ldA = [&](int b, int mi, int kk) -> bf16x8 {
        return *(const bf16x8*)(AsB + b * ABYTES + (aRow + mi * 16) * 128
                                + (kk ? swz1 : swz));
    };
    auto ldB = [&](int b, int ni, int kk) -> bf16x8 {
        return *(const bf16x8*)(BsB + b * 32768 + (bRow + ni * 16) * 128
                                + (kk ? swz1 : swz));
    };

    f32x4 acc[MI][4];
#pragma unroll
    for (int i = 0; i < MI; i++)
#pragma unroll
        for (int j = 0; j < 4; j++)
            acc[i][j] = (f32x4){0.f, 0.f, 0.f, 0.f};

    stA(0, 0); stB(0, 0);
    asm volatile("s_waitcnt vmcnt(0)" ::: "memory");
    __builtin_amdgcn_s_barrier();
    __builtin_amdgcn_sched_barrier(0);

    for (int t = 0; t < NT; ++t) {
        const int rb = t & 1;
        const int wb = rb ^ 1;

        bf16x8 bfr[4][2];
#pragma unroll
        for (int ni = 0; ni < 4; ni++)
#pragma unroll
            for (int kk = 0; kk < 2; kk++)
                bfr[ni][kk] = ldB(rb, ni, kk);
        bf16x8 a0[2][2];
#pragma unroll
        for (int i = 0; i < 2; i++)
#pragma unroll
            for (int kk = 0; kk < 2; kk++)
                a0[i][kk] = ldA(rb, i, kk);

        if (t + 1 < NT) { stB(t + 1, wb); stA(t + 1, wb); }

        __builtin_amdgcn_s_setprio(1);
#pragma unroll
        for (int kk = 0; kk < 2; kk++)
#pragma unroll
            for (int i = 0; i < 2; i++)
#pragma unroll
                for (int ni = 0; ni < 4; ni++)
                    acc[i][ni] = MFMA16(a0[i][kk], bfr[ni][kk], acc[i][ni]);
        __builtin_amdgcn_s_setprio(0);

#pragma unroll
        for (int p = 1; p < MI / 2; ++p) {
            bf16x8 ap[2][2];
#pragma unroll
            for (int i = 0; i < 2; i++)
#pragma unroll
                for (int kk = 0; kk < 2; kk++)
                    ap[i][kk] = ldA(rb, 2 * p + i, kk);
            __builtin_amdgcn_s_setprio(1);
#pragma unroll
            for (int kk = 0; kk < 2; kk++)
#pragma unroll
                for (int i = 0; i < 2; i++)
#pragma unroll
                    for (int ni = 0; ni < 4; ni++)
                        acc[2 * p + i][ni] =
                            MFMA16(ap[i][kk], bfr[ni][kk], acc[2 * p + i][ni]);
            __builtin_amdgcn_s_setprio(0);
        }

        asm volatile("s_waitcnt vmcnt(0)" ::: "memory");
        __builtin_amdgcn_s_barrier();
        __builtin_amdgcn_sched_barrier(0);
    }

#pragma unroll
    for (int mi = 0; mi < MI; mi++) {
        int rowb = m0 + wr * (MI * 16) + mi * 16 + quad * 4;
#pragma unroll
        for (int ni = 0; ni < 4; ni++) {
            int col = n0 + wc * 64 + ni * 16 + row16;
#pragma unroll
            for (int r = 0; r < 4; r++) {
                size_t idx = (size_t)(rowb + r) * N + col;
                float  v   = acc[mi][ni][r];
                if (oF) ((float*)C)[idx] = v;
                else    ((bf16*)C)[idx]  = __float2bfloat16(v);
            }
        }
    }
}

// ---------------------------------------------------------------------------
// RoPE + RMSNorm in place in qkv; q additionally scaled by QSCALE. (unchanged)
__global__ __launch_bounds__(256)
void rope_rms(bf16* __restrict__ qkv, const void* __restrict__ cosp,
              const void* __restrict__ sinp, const int* __restrict__ flagp)
{
    const bool f = *flagp != 0;
    const int wg   = blockIdx.x * 4 + (threadIdx.x >> 6);
    const int lane = threadIdx.x & 63;
    const int s    = wg % 20;
    const int m    = wg / 20;
    const int t    = m & (TSEQ - 1);

    const int col = (s < 16) ? s * HD : CE + (s - 16) * HD;
    bf16* p = qkv + (size_t)m * NQKV + col;

    float xlo = __bfloat162float(p[lane]);
    float xhi = __bfloat162float(p[lane + 64]);
    float cl  = ldf(cosp, t * HD + lane, f);
    float sl  = ldf(sinp, t * HD + lane, f);
    float ch  = ldf(cosp, t * HD + 64 + lane, f);
    float sh  = ldf(sinp, t * HD + 64 + lane, f);

    float rlo = xlo * cl - xhi * sl;
    float rhi = xhi * ch + xlo * sh;

    float ss = rlo * rlo + rhi * rhi;
#pragma unroll
    for (int off = 32; off > 0; off >>= 1)
        ss += __shfl_xor(ss, off, 64);
    float inv = rsqrtf(ss * (1.0f / 128.0f) + 1.1920929e-07f);
    if (s < 16) inv *= QSCALE;

    p[lane]      = __float2bfloat16(rlo * inv);
    p[lane + 64] = __float2bfloat16(rhi * inv);
}

// ---------------------------------------------------------------------------
// vt[b, hk, d, t] = qkv[(b*T+t)*3072 + 2560 + hk*128 + d]  (unchanged)
__global__ __launch_bounds__(256)
void vtrans(const bf16* __restrict__ qkv, bf16* __restrict__ vt)
{
    int idx = blockIdx.x * 256 + threadIdx.x;
    int t  = idx & (TSEQ - 1);
    int d  = (idx >> 11) & 127;
    int bh = idx >> 18;
    vt[idx] = qkv[((size_t)((bh >> 2) * TSEQ + t)) * NQKV + 2560 + (bh & 3) * HD + d];
}

// ---------------------------------------------------------------------------
// Flash attention R12: 2-blocks/CU occupancy push.
// R4 counters: 73us, MfmaUtil 19%, Occupancy 20.8% (cap 25% -- 1 block/CU at
// 82KB LDS, 2 waves/SIMD). Stall-bound: per-tile vmcnt(0)+barrier and the
// serial QK->softmax->PV chain have no co-resident independent work to hide
// under. Fix:
//  (a) LDS 82->80KB exactly: Pl[8][16][72](pad) -> Pl[8][16][64] with XOR
//      chunk swizzle phys16B = chunk ^ (row&7). Reads stay 2-way, writes
//      ~4-way (same as the 72-pad) -- conflict-neutral, -2KB. 2x80KB = the
//      full 160KB pool -> 2 independent blocks/CU (m114 overlap).
//  (b) grid 256->512 blocks: one 32-row q-tile per block, LPT order
//      (xi = 63 - blockIdx.x, longest first). Robust to both occupancy
//      outcomes: 2/CU -> TLP win; 1/CU -> makespan ~= paired schedule.
__global__ __launch_bounds__(512, 4)
void attn(bf16* __restrict__ qkv, const bf16* __restrict__ vt)
{
    __shared__ __bf16 Ks[2][64][128];   // swizzled image, 2x16KB
    __shared__ __bf16 Vs[2][128][64];   // swizzled image, 2x16KB
    __shared__ __bf16 Pl[8][16][64];    // per-wave P transpose, XOR-swz, 16KB

    const int tid   = threadIdx.x;
    const int lane  = tid & 63;
    const int wid   = tid >> 6;
    const int row16 = lane & 15;
    const int quad  = lane >> 4;
    const int b   = blockIdx.y >> 2;
    const int hk  = blockIdx.y & 3;
    const int h   = hk * 4 + (wid & 3);   // wave's q-head
    const int mh  = wid >> 2;             // wave's 16-row half of the 32-row tile

    const int xi  = 63 - blockIdx.x;      // LPT: longest block first
    const int nkt = (xi >> 1) + 1;        // causal k-tiles (64-wide)
    const int qr0 = xi * 32 + mh * 16;    // wave's first q row

    const bf16* Kp = qkv + ((size_t)(b * TSEQ)) * NQKV + CE + hk * HD;
    const bf16* Vp = vt + ((size_t)(b * 4 + hk) * HD) * TSEQ;

    char* const KsB = (char*)Ks;
    char* const VsB = (char*)Vs;
    char* const PlB = (char*)Pl;

    // staging: wave w owns K rows [8w,8w+8), V rows [16w,16w+16);
    // linear LDS dest, swizzle via pre-swizzled per-lane GLOBAL address.
    auto stage = [&](int buf, int k0) {
#pragma unroll
        for (int i = 0; i < 2; i++) {
            int kr = (wid << 3) + i * 4 + (lane >> 4);
            int kc = (lane & 15) ^ (kr & 7);
            gld16(Kp + (size_t)(k0 + kr) * NQKV + kc * 8,
                  KsB + buf * 16384 + ((wid << 3) + i * 4) * 256 + lane * 16);
            int vr = (wid << 4) + i * 8 + (lane >> 3);
            int vc = (lane & 7) ^ (vr & 7);
            gld16(Vp + (size_t)vr * TSEQ + k0 + vc * 8,
                  VsB + buf * 16384 + ((wid << 4) + i * 8) * 128 + lane * 16);
        }
    };

    const bf16* Q = qkv + ((size_t)(b * TSEQ + qr0)) * NQKV + h * HD;
    bf16x8 aq[4];
#pragma unroll
    for (int ds = 0; ds < 4; ds++)
        aq[ds] = *(const bf16x8*)(Q + (size_t)row16 * NQKV + ds * 32 + quad * 8);

    f32x4 o[8];
#pragma unroll
    for (int dt = 0; dt < 8; dt++) o[dt] = (f32x4){0.f, 0.f, 0.f, 0.f};
    float lsum[4] = {0.f, 0.f, 0.f, 0.f};

    stage(0, 0);
    __syncthreads();          // tile 0 landed

    for (int t = 0; t < nkt; ++t) {
        const int cur = t & 1;
        if (t + 1 < nkt) stage(cur ^ 1, (t + 1) * 64);   // prefetch

        // QK^T: 16 MFMA
        f32x4 s[4];
#pragma unroll
        for (int kg = 0; kg < 4; kg++) s[kg] = (f32x4){0.f, 0.f, 0.f, 0.f};
        __builtin_amdgcn_s_setprio(1);
#pragma unroll
        for (int ds = 0; ds < 4; ds++) {
#pragma unroll
            for (int kg = 0; kg < 4; kg++) {
                int krow = kg * 16 + row16;
                int phys = (ds * 4 + quad) ^ (row16 & 7);
                bf16x8 kf = *(const bf16x8*)(KsB + cur * 16384 + krow * 256 + phys * 16);
                s[kg] = MFMA16(aq[ds], kf, s[kg]);
            }
        }
        __builtin_amdgcn_s_setprio(0);

        // fixed-max softmax numerators; per-lane partial sums; P -> LDS
        // Pl write: row=quad*4+r, col=kg*16+row16; XOR-swz image:
        // byte = wid*2048 + row*128 + ((kg*2+(row16>>3)) ^ (row&7))*16
        //        + (row16&7)*2
        const bool diag = (t == nkt - 1);
        const int  k0   = t * 64;
        const int  r16h = row16 >> 3;
        const int  r16l = (row16 & 7) * 2;
#pragma unroll
        for (int r = 0; r < 4; r++) {
            float pv[4];
            int prow = quad * 4 + r;
            int qrow = qr0 + prow;
#pragma unroll
            for (int kg = 0; kg < 4; kg++) {
                float e = __builtin_amdgcn_exp2f(s[kg][r] - M2);
                pv[kg] = (!diag || (k0 + kg * 16 + row16 <= qrow)) ? e : 0.f;
            }
            lsum[r] += (pv[0] + pv[1]) + (pv[2] + pv[3]);
#pragma unroll
            for (int kg = 0; kg < 4; kg++)
                *(__bf16*)(PlB + wid * 2048 + prow * 128
                           + (((kg * 2 + r16h) ^ (prow & 7)) << 4) + r16l)
                    = (__bf16)pv[kg];
        }
        __asm__ volatile("" ::: "memory");

        // PV: 16 MFMA. Pl read: row=row16, chunk=c*4+quad, phys=chunk^(row16&7)
        __builtin_amdgcn_s_setprio(1);
#pragma unroll
        for (int c = 0; c < 2; c++) {
            bf16x8 pf = *(const bf16x8*)(PlB + wid * 2048 + row16 * 128
                                         + ((((c << 2) + quad) ^ (row16 & 7)) << 4));
#pragma unroll
            for (int dt = 0; dt < 8; dt++) {
                int vrow = dt * 16 + row16;
                int phys = (c * 4 + quad) ^ (row16 & 7);
                bf16x8 vf = *(const bf16x8*)(VsB + cur * 16384 + vrow * 128 + phys * 16);
                o[dt] = MFMA16(pf, vf, o[dt]);
            }
        }
        __builtin_amdgcn_s_setprio(0);
        __asm__ volatile("" ::: "memory");
        __syncthreads();   // reads of `cur` done; prefetch landed
    }

    // final 16-lane reduction of l per row; write O into qkv's Q slot
#pragma unroll
    for (int r = 0; r < 4; r++) {
        float l = lsum[r];
#pragma unroll
        for (int off = 1; off < 16; off <<= 1)
            l += __shfl_xor(l, off, 64);
        float rl = 1.0f / l;
        int trow = qr0 + quad * 4 + r;
        bf16* dst = qkv + ((size_t)(b * TSEQ + trow)) * NQKV + h * HD;
#pragma unroll
        for (int dt = 0; dt < 8; dt++)
            dst[dt * 16 + row16] = __float2bfloat16(o[dt][r] * rl);
    }
}

// ---------------------------------------------------------------------------
extern "C" void kernel_launch(void* const* d_in, const int* in_sizes, int n_in,
                              void* d_out, int out_size, void* d_ws, size_t ws_size,
                              hipStream_t stream)
{
    // ws (bf16 elems): qkv [4096,3072] 25.2MB | vt 4.2MB | wqkvb [3072,2048]
    // 12.6MB (reused for wprojb after gemm1) | flag | xb [4096,2048] 16.8MB.
    bf16* qkv   = (bf16*)d_ws;
    bf16* vt    = qkv + (size_t)BT * NQKV;
    bf16* wqkvb = vt + (size_t)2 * 4 * HD * TSEQ;
    int* flagp  = (int*)(wqkvb + (size_t)NQKV * CE);
    bf16* xb    = wqkvb + (size_t)NQKV * CE + 16;   // 32B after flag, 16B-aligned

    const size_t need = ((size_t)BT * NQKV + (size_t)2 * 4 * HD * TSEQ
                         + (size_t)NQKV * CE + 16 + (size_t)BT * CE) * sizeof(bf16);
    const bool useXb = ws_size >= need;

    // 0) detect input dtype -> device flag
    detect_dtype<<<1, 256, 0, stream>>>((const unsigned short*)d_in[0], flagp);

    // 1) convert wq/wk/wv to fused bf16 [3072][2048]
    conv_bf16<<<(2048 * 2048 / 8) / 256, 256, 0, stream>>>(d_in[3], wqkvb, flagp);
    conv_bf16<<<(512 * 2048 / 8) / 256, 256, 0, stream>>>(d_in[4], wqkvb + (size_t)2048 * 2048, flagp);
    conv_bf16<<<(512 * 2048 / 8) / 256, 256, 0, stream>>>(d_in[5], wqkvb + (size_t)2560 * 2048, flagp);

    // 2) fused QKV projection
    if (useXb) {
        conv_bf16<<<(BT * CE / 8) / 256, 256, 0, stream>>>(d_in[0], xb, flagp);
        gemmP<8><<<dim3(NQKV / 256, BT / 256), 512, 0, stream>>>(
            xb, wqkvb, qkv, BT, NQKV, CE, CE, 0, flagp);
    } else {
        gemm_bt<<<dim3(NQKV / 128, BT / 128), 256, 0, stream>>>(
            d_in[0], wqkvb, qkv, BT, NQKV, CE, CE, 1, 0, flagp);
    }

    // 3) convert wproj into the same buffer (stream-ordered after gemm1)
    conv_bf16<<<(2048 * 2048 / 8) / 256, 256, 0, stream>>>(d_in[6], wqkvb, flagp);

    // 4) V transpose to [B,KV,D,T]
    vtrans<<<(2 * 4 * HD * TSEQ) / 256, 256, 0, stream>>>(qkv, vt);

    // 5) RoPE + RMSNorm in place (q scaled by QSCALE)
    rope_rms<<<(BT * 20) / 4, 256, 0, stream>>>(qkv, d_in[1], d_in[2], flagp);

    // 6) balanced GQA-fused flash attention; O overwrites qkv's Q columns
    attn<<<dim3(64, 2 * 4), 512, 0, stream>>>(qkv, vt);

    // 7) output projection: A=qkv cols 0..2047 (bf16, lda=3072)
    if (useXb) {
        gemmP<4><<<dim3(CE / 256, BT / 128), 512, 0, stream>>>(
            qkv, wqkvb, d_out, BT, CE, CE, NQKV, 1, flagp);
    } else {
        gemm_bt<<<dim3(CE / 128, BT / 128), 256, 0, stream>>>(
            qkv, wqkvb, d_out, BT, CE, CE, NQKV, 0, 1, flagp);
    }
}

// Round 7
// 320.967 us; speedup vs baseline: 1.0770x; 1.0770x over previous
//
#include <hip/hip_runtime.h>
#include <hip/hip_bf16.h>

typedef __hip_bfloat16 bf16;
typedef __attribute__((ext_vector_type(8))) __bf16 bf16x8;
typedef __attribute__((ext_vector_type(4))) float f32x4;

#define MFMA16(a, b, c) __builtin_amdgcn_mfma_f32_16x16x32_bf16((a), (b), (c), 0, 0, 0)

#define BT 4096      // B*T rows
#define CE 2048      // embed dim
#define NQKV 3072    // q(2048) + k(512) + v(512)
#define TSEQ 2048
#define HD 128

// q pre-scale: 1/sqrt(128) * log2(e), folded into rope_rms's q output.
#define QSCALE (0.08838834764831845f * 1.4426950408889634f)
// fixed softmax max bound: ||q'||*||k|| = 128*QSCALE (Cauchy-Schwarz on
// RMS-normalized vectors). p = 2^(s' - M2) <= ~1, no online max needed.
#define M2 16.3222f

// ---------------------------------------------------------------------------
// async global->LDS 16B copy (one instruction, no VGPR round trip)
__device__ __forceinline__ void gld16(const void* g, void* l)
{
    __builtin_amdgcn_global_load_lds(
        (const __attribute__((address_space(1))) void*)g,
        (__attribute__((address_space(3))) void*)l, 16, 0, 0);
}

// ---------------------------------------------------------------------------
// Input-dtype detector (inputs are fp32; gate kept for safety).
__global__ void detect_dtype(const unsigned short* __restrict__ x, int* __restrict__ flag)
{
    __shared__ int cnt;
    if (threadIdx.x == 0) cnt = 0;
    __syncthreads();
    unsigned short w = x[2 * threadIdx.x];
    int e = (w >> 7) & 0xFF;
    atomicAdd(&cnt, (e >= 117 && e <= 130) ? 1 : 0);
    __syncthreads();
    if (threadIdx.x == 0) *flag = (cnt < 128) ? 1 : 0;
}

// Stage 8 elems (16B bf16) into LDS from bf16 or fp32 source (VGPR convert).
__device__ __forceinline__ void stage8(short* dst, const void* src, size_t eoff, bool f32)
{
    if (f32) {
        const float* s = (const float*)src + eoff;
        float4 f0 = *(const float4*)s;
        float4 f1 = *(const float4*)(s + 4);
        bf16x8 v;
        v[0] = (__bf16)f0.x; v[1] = (__bf16)f0.y; v[2] = (__bf16)f0.z; v[3] = (__bf16)f0.w;
        v[4] = (__bf16)f1.x; v[5] = (__bf16)f1.y; v[6] = (__bf16)f1.z; v[7] = (__bf16)f1.w;
        *(bf16x8*)dst = v;
    } else {
        *(uint4*)dst = *(const uint4*)((const bf16*)src + eoff);
    }
}

__device__ __forceinline__ float ldf(const void* p, int i, bool f32)
{
    return f32 ? ((const float*)p)[i] : __bfloat162float(((const bf16*)p)[i]);
}

// ---------------------------------------------------------------------------
// fp32 (or bf16) -> bf16 conversion, 8 elems/thread.
__global__ __launch_bounds__(256)
void conv_bf16(const void* __restrict__ src, bf16* __restrict__ dst,
               const int* __restrict__ flagp)
{
    const bool f = *flagp != 0;
    size_t i8 = (size_t)blockIdx.x * 256 + threadIdx.x;
    stage8((short*)(dst + i8 * 8), src, i8 * 8, f);
}

// ---------------------------------------------------------------------------
// Legacy 128^2 GEMM, kept ONLY as ws-constrained fallback (fp32-A staging).
__global__ __launch_bounds__(256)
void gemm_bt(const void* __restrict__ A, const bf16* __restrict__ W,
             void* __restrict__ C, int M, int N, int K, int lda,
             int aGate, int oGate, const int* __restrict__ flagp)
{
    __shared__ short As[128][32];
    __shared__ short Bs[128][32];

    const int f = *flagp;
    const bool aF = aGate && f, oF = oGate && f;

    const int tid   = threadIdx.x;
    const int lane  = tid & 63;
    const int wid   = tid >> 6;
    const int row16 = lane & 15;
    const int quad  = lane >> 4;
    const int wr    = wid >> 1;
    const int wc    = wid & 1;
    const int m0    = blockIdx.y * 128;
    const int n0    = blockIdx.x * 128;

    const int rl4 = wid * 16 + (lane >> 2);
    const int c8  = (lane & 3) * 8;

    f32x4 acc[4][4];
#pragma unroll
    for (int i = 0; i < 4; i++)
#pragma unroll
        for (int j = 0; j < 4; j++)
            acc[i][j] = (f32x4){0.f, 0.f, 0.f, 0.f};

    for (int k0 = 0; k0 < K; k0 += 32) {
#pragma unroll
        for (int i = 0; i < 2; i++) {
            int r = i * 64 + rl4;
            gld16(W + (size_t)(n0 + r) * K + k0 + c8, &Bs[r][c8]);
        }
        if (!aF) {
#pragma unroll
            for (int i = 0; i < 2; i++) {
                int r = i * 64 + rl4;
                gld16((const bf16*)A + (size_t)(m0 + r) * lda + k0 + c8, &As[r][c8]);
            }
        } else {
#pragma unroll
            for (int i = 0; i < 2; i++) {
                int c = i * 256 + tid;
                int row = c >> 2, col = (c & 3) << 3;
                stage8(&As[row][col], A, (size_t)(m0 + row) * lda + k0 + col, true);
            }
        }
        __syncthreads();

        bf16x8 af[4], bfv[4];
#pragma unroll
        for (int mi = 0; mi < 4; mi++)
            af[mi] = *(const bf16x8*)&As[wr * 64 + mi * 16 + row16][quad * 8];
#pragma unroll
        for (int ni = 0; ni < 4; ni++)
            bfv[ni] = *(const bf16x8*)&Bs[wc * 64 + ni * 16 + row16][quad * 8];
#pragma unroll
        for (int mi = 0; mi < 4; mi++)
#pragma unroll
            for (int ni = 0; ni < 4; ni++)
                acc[mi][ni] = MFMA16(af[mi], bfv[ni], acc[mi][ni]);
        __syncthreads();
    }

#pragma unroll
    for (int mi = 0; mi < 4; mi++) {
        int rowb = m0 + wr * 64 + mi * 16 + quad * 4;
#pragma unroll
        for (int ni = 0; ni < 4; ni++) {
            int col = n0 + wc * 64 + ni * 16 + row16;
#pragma unroll
            for (int r = 0; r < 4; r++) {
                size_t idx = (size_t)(rowb + r) * N + col;
                float  v   = acc[mi][ni][r];
                if (oF) ((float*)C)[idx] = v;
                else    ((bf16*)C)[idx]  = __float2bfloat16(v);
            }
        }
    }
}

// ---------------------------------------------------------------------------
// R11 GEMM (verified R4) + bijective XCD-aware block swizzle (T1).
// BM=MI*32 x BN=256, BK=64, 512 thr / 8 waves, double-buffered LDS, one
// vmcnt(0)+barrier per 64-K window, full-row XOR swizzle via pre-swizzled
// global source. Grids (192 / 128 blocks) are %8==0 -> swizzle bijective:
// XCD x gets the contiguous logical-tile chunk [x*cpx, (x+1)*cpx) so
// neighbor tiles sharing A/B panels hit the same per-XCD L2.
template<int MI>
__global__ __launch_bounds__(512, 2)
void gemmP(const bf16* __restrict__ A, const bf16* __restrict__ W,
           void* __restrict__ C, int M, int N, int K, int lda,
           int oGate, const int* __restrict__ flagp)
{
    constexpr int BM     = MI * 32;
    constexpr int ABYTES = BM * 128;        // bytes per A K-tile (BK=64 bf16)
    constexpr int AUL    = ABYTES / 8192;   // gld16 per thread for A (4 or 2)

    __shared__ __bf16 As[2][BM][64];
    __shared__ __bf16 Bs[2][256][64];

    const bool oF = oGate && (*flagp != 0);

    // XCD swizzle: hardware slot lin -> logical tile swz (bijective, nwg%8==0)
    const int gx  = gridDim.x;
    const int lin = blockIdx.y * gx + blockIdx.x;
    const int cpx = (gx * gridDim.y) >> 3;
    const int swzid = (lin & 7) * cpx + (lin >> 3);
    const int bx = swzid % gx;
    const int by = swzid / gx;

    const int tid   = threadIdx.x;
    const int lane  = tid & 63;
    const int wid   = tid >> 6;
    const int row16 = lane & 15;
    const int quad  = lane >> 4;
    const int wr    = wid >> 2;          // 0..1
    const int wc    = wid & 3;           // 0..3
    const int m0    = by * BM;
    const int n0    = bx * 256;
    const int NT    = K >> 6;            // 64-wide K-tiles

    const int srow = tid >> 3;                        // 0..63
    const int sc8  = ((tid & 7) ^ (srow & 7)) * 8;    // element offset
    const bf16* Ag = A + (size_t)(m0 + srow) * lda + sc8;
    const bf16* Bg = W + (size_t)(n0 + srow) * K   + sc8;
    char* const AsB = (char*)As;
    char* const BsB = (char*)Bs;
    const int sdst = tid * 16;

    auto stA = [&](int kt, int b) {
#pragma unroll
        for (int u = 0; u < AUL; ++u)
            gld16(Ag + (size_t)(u * 64) * lda + kt * 64,
                  AsB + b * ABYTES + u * 8192 + sdst);
    };
    auto stB = [&](int kt, int b) {
#pragma unroll
        for (int u = 0; u < 4; ++u)
            gld16(Bg + (size_t)(u * 64) * K + kt * 64,
                  BsB + b * 32768 + u * 8192 + sdst);
    };

    const int swz  = ((quad ^ (row16 & 7)) * 16);          // kk=0
    const int swz1 = (((4 + quad) ^ (row16 & 7)) * 16);    // kk=1
    const int aRow = wr * (MI * 16) + row16;
    const int bRow = wc * 64 + row16;

    auto ldA = [&](int b, int mi, int kk) -> bf16x8 {
        return *(const bf16x8*)(AsB + b * ABYTES + (aRow + mi * 16) * 128
                                + (kk ? swz1 : swz));
    };
    auto ldB = [&](int b, int ni, int kk) -> bf16x8 {
        return *(const bf16x8*)(BsB + b * 32768 + (bRow + ni * 16) * 128
                                + (kk ? swz1 : swz));
    };

    f32x4 acc[MI][4];
#pragma unroll
    for (int i = 0; i < MI; i++)
#pragma unroll
        for (int j = 0; j < 4; j++)
            acc[i][j] = (f32x4){0.f, 0.f, 0.f, 0.f};

    stA(0, 0); stB(0, 0);
    asm volatile("s_waitcnt vmcnt(0)" ::: "memory");
    __builtin_amdgcn_s_barrier();
    __builtin_amdgcn_sched_barrier(0);

    for (int t = 0; t < NT; ++t) {
        const int rb = t & 1;
        const int wb = rb ^ 1;

        bf16x8 bfr[4][2];
#pragma unroll
        for (int ni = 0; ni < 4; ni++)
#pragma unroll
            for (int kk = 0; kk < 2; kk++)
                bfr[ni][kk] = ldB(rb, ni, kk);
        bf16x8 a0[2][2];
#pragma unroll
        for (int i = 0; i < 2; i++)
#pragma unroll
            for (int kk = 0; kk < 2; kk++)
                a0[i][kk] = ldA(rb, i, kk);

        if (t + 1 < NT) { stB(t + 1, wb); stA(t + 1, wb); }

        __builtin_amdgcn_s_setprio(1);
#pragma unroll
        for (int kk = 0; kk < 2; kk++)
#pragma unroll
            for (int i = 0; i < 2; i++)
#pragma unroll
                for (int ni = 0; ni < 4; ni++)
                    acc[i][ni] = MFMA16(a0[i][kk], bfr[ni][kk], acc[i][ni]);
        __builtin_amdgcn_s_setprio(0);

#pragma unroll
        for (int p = 1; p < MI / 2; ++p) {
            bf16x8 ap[2][2];
#pragma unroll
            for (int i = 0; i < 2; i++)
#pragma unroll
                for (int kk = 0; kk < 2; kk++)
                    ap[i][kk] = ldA(rb, 2 * p + i, kk);
            __builtin_amdgcn_s_setprio(1);
#pragma unroll
            for (int kk = 0; kk < 2; kk++)
#pragma unroll
                for (int i = 0; i < 2; i++)
#pragma unroll
                    for (int ni = 0; ni < 4; ni++)
                        acc[2 * p + i][ni] =
                            MFMA16(ap[i][kk], bfr[ni][kk], acc[2 * p + i][ni]);
            __builtin_amdgcn_s_setprio(0);
        }

        asm volatile("s_waitcnt vmcnt(0)" ::: "memory");
        __builtin_amdgcn_s_barrier();
        __builtin_amdgcn_sched_barrier(0);
    }

#pragma unroll
    for (int mi = 0; mi < MI; mi++) {
        int rowb = m0 + wr * (MI * 16) + mi * 16 + quad * 4;
#pragma unroll
        for (int ni = 0; ni < 4; ni++) {
            int col = n0 + wc * 64 + ni * 16 + row16;
#pragma unroll
            for (int r = 0; r < 4; r++) {
                size_t idx = (size_t)(rowb + r) * N + col;
                float  v   = acc[mi][ni][r];
                if (oF) ((float*)C)[idx] = v;
                else    ((bf16*)C)[idx]  = __float2bfloat16(v);
            }
        }
    }
}

// ---------------------------------------------------------------------------
// RoPE + RMSNorm in place in qkv; q additionally scaled by QSCALE. (unchanged)
__global__ __launch_bounds__(256)
void rope_rms(bf16* __restrict__ qkv, const void* __restrict__ cosp,
              const void* __restrict__ sinp, const int* __restrict__ flagp)
{
    const bool f = *flagp != 0;
    const int wg   = blockIdx.x * 4 + (threadIdx.x >> 6);
    const int lane = threadIdx.x & 63;
    const int s    = wg % 20;
    const int m    = wg / 20;
    const int t    = m & (TSEQ - 1);

    const int col = (s < 16) ? s * HD : CE + (s - 16) * HD;
    bf16* p = qkv + (size_t)m * NQKV + col;

    float xlo = __bfloat162float(p[lane]);
    float xhi = __bfloat162float(p[lane + 64]);
    float cl  = ldf(cosp, t * HD + lane, f);
    float sl  = ldf(sinp, t * HD + lane, f);
    float ch  = ldf(cosp, t * HD + 64 + lane, f);
    float sh  = ldf(sinp, t * HD + 64 + lane, f);

    float rlo = xlo * cl - xhi * sl;
    float rhi = xhi * ch + xlo * sh;

    float ss = rlo * rlo + rhi * rhi;
#pragma unroll
    for (int off = 32; off > 0; off >>= 1)
        ss += __shfl_xor(ss, off, 64);
    float inv = rsqrtf(ss * (1.0f / 128.0f) + 1.1920929e-07f);
    if (s < 16) inv *= QSCALE;

    p[lane]      = __float2bfloat16(rlo * inv);
    p[lane + 64] = __float2bfloat16(rhi * inv);
}

// ---------------------------------------------------------------------------
// vtrans: LDS-tiled transpose (old version read qkv at stride 6KB -- 2
// useful bytes per 64B line, ~32x read amplification). Per block: one 64t x
// 128d tile of one (b,hk); coalesced 16B reads along d, coalesced 16B writes
// along t. Pad 136 breaks the write-gather bank alias.
__global__ __launch_bounds__(256)
void vtrans(const bf16* __restrict__ qkv, bf16* __restrict__ vt)
{
    __shared__ __bf16 tl[64][136];

    const int tid = threadIdx.x;
    const int bh  = blockIdx.x >> 5;          // 0..7 = b*4+hk
    const int t0  = (blockIdx.x & 31) * 64;
    const int b   = bh >> 2;
    const int hk  = bh & 3;

    const bf16* src = qkv + ((size_t)(b * TSEQ + t0)) * NQKV + 2560 + hk * HD;
#pragma unroll
    for (int it = 0; it < 4; ++it) {
        int idx  = it * 256 + tid;
        int trow = idx >> 4;
        int dcol = (idx & 15) * 8;
        *(uint4*)&tl[trow][dcol] = *(const uint4*)(src + (size_t)trow * NQKV + dcol);
    }
    __syncthreads();

    bf16* dst = vt + ((size_t)(bh * HD)) * TSEQ + t0;
#pragma unroll
    for (int it = 0; it < 4; ++it) {
        int idx  = it * 256 + tid;
        int drow = idx >> 3;
        int tcol = (idx & 7) * 8;
        bf16x8 v;
#pragma unroll
        for (int j = 0; j < 8; ++j)
            v[j] = tl[tcol + j][drow];
        *(bf16x8*)(dst + (size_t)drow * TSEQ + tcol) = v;
    }
}

// ---------------------------------------------------------------------------
// Flash attention = R4's verified paired-balanced structure (73us) with
// R5's verified Pl XOR-swizzle body (80KB LDS, 64 VGPR). Block p does tiles
// {p, 63-p} (constant 33 k-tile iterations, 256 blocks, single round).
__global__ __launch_bounds__(512, 2)
void attn(bf16* __restrict__ qkv, const bf16* __restrict__ vt)
{
    __shared__ __bf16 Ks[2][64][128];   // swizzled image, 2x16KB
    __shared__ __bf16 Vs[2][128][64];   // swizzled image, 2x16KB
    __shared__ __bf16 Pl[8][16][64];    // per-wave P transpose, XOR-swz, 16KB

    const int tid   = threadIdx.x;
    const int lane  = tid & 63;
    const int wid   = tid >> 6;
    const int row16 = lane & 15;
    const int quad  = lane >> 4;
    const int b   = blockIdx.y >> 2;
    const int hk  = blockIdx.y & 3;
    const int h   = hk * 4 + (wid & 3);   // wave's q-head
    const int mh  = wid >> 2;             // wave's 16-row half of the 32-row tile
    const int p   = blockIdx.x;           // 0..31

    const bf16* Kp = qkv + ((size_t)(b * TSEQ)) * NQKV + CE + hk * HD;
    const bf16* Vp = vt + ((size_t)(b * 4 + hk) * HD) * TSEQ;

    char* const KsB = (char*)Ks;
    char* const VsB = (char*)Vs;
    char* const PlB = (char*)Pl;

    auto stage = [&](int buf, int k0) {
#pragma unroll
        for (int i = 0; i < 2; i++) {
            int kr = (wid << 3) + i * 4 + (lane >> 4);
            int kc = (lane & 15) ^ (kr & 7);
            gld16(Kp + (size_t)(k0 + kr) * NQKV + kc * 8,
                  KsB + buf * 16384 + ((wid << 3) + i * 4) * 256 + lane * 16);
            int vr = (wid << 4) + i * 8 + (lane >> 3);
            int vc = (lane & 7) ^ (vr & 7);
            gld16(Vp + (size_t)vr * TSEQ + k0 + vc * 8,
                  VsB + buf * 16384 + ((wid << 4) + i * 8) * 128 + lane * 16);
        }
    };

    for (int pass = 0; pass < 2; ++pass) {
        const int xi  = pass ? 63 - p : p;     // 32-row q-tile index 0..63
        const int nkt = (xi >> 1) + 1;         // causal k-tiles (64-wide)
        const int qr0 = xi * 32 + mh * 16;     // wave's first q row

        const bf16* Q = qkv + ((size_t)(b * TSEQ + qr0)) * NQKV + h * HD;
        bf16x8 aq[4];
#pragma unroll
        for (int ds = 0; ds < 4; ds++)
            aq[ds] = *(const bf16x8*)(Q + (size_t)row16 * NQKV + ds * 32 + quad * 8);

        f32x4 o[8];
#pragma unroll
        for (int dt = 0; dt < 8; dt++) o[dt] = (f32x4){0.f, 0.f, 0.f, 0.f};
        float lsum[4] = {0.f, 0.f, 0.f, 0.f};

        __syncthreads();          // prior pass's LDS reads complete
        stage(0, 0);
        __syncthreads();          // tile 0 landed

        for (int t = 0; t < nkt; ++t) {
            const int cur = t & 1;
            if (t + 1 < nkt) stage(cur ^ 1, (t + 1) * 64);   // prefetch

            // QK^T: 16 MFMA
            f32x4 s[4];
#pragma unroll
            for (int kg = 0; kg < 4; kg++) s[kg] = (f32x4){0.f, 0.f, 0.f, 0.f};
            __builtin_amdgcn_s_setprio(1);
#pragma unroll
            for (int ds = 0; ds < 4; ds++) {
#pragma unroll
                for (int kg = 0; kg < 4; kg++) {
                    int krow = kg * 16 + row16;
                    int phys = (ds * 4 + quad) ^ (row16 & 7);
                    bf16x8 kf = *(const bf16x8*)(KsB + cur * 16384 + krow * 256 + phys * 16);
                    s[kg] = MFMA16(aq[ds], kf, s[kg]);
                }
            }
            __builtin_amdgcn_s_setprio(0);

            // fixed-max softmax numerators; per-lane partial sums; P -> LDS
            // Pl write: row=quad*4+r, col=kg*16+row16; XOR-swz image:
            // byte = wid*2048 + row*128 + ((kg*2+(row16>>3)) ^ (row&7))*16
            //        + (row16&7)*2
            const bool diag = (t == nkt - 1);
            const int  k0   = t * 64;
            const int  r16h = row16 >> 3;
            const int  r16l = (row16 & 7) * 2;
#pragma unroll
            for (int r = 0; r < 4; r++) {
                float pv[4];
                int prow = quad * 4 + r;
                int qrow = qr0 + prow;
#pragma unroll
                for (int kg = 0; kg < 4; kg++) {
                    float e = __builtin_amdgcn_exp2f(s[kg][r] - M2);
                    pv[kg] = (!diag || (k0 + kg * 16 + row16 <= qrow)) ? e : 0.f;
                }
                lsum[r] += (pv[0] + pv[1]) + (pv[2] + pv[3]);
#pragma unroll
                for (int kg = 0; kg < 4; kg++)
                    *(__bf16*)(PlB + wid * 2048 + prow * 128
                               + (((kg * 2 + r16h) ^ (prow & 7)) << 4) + r16l)
                        = (__bf16)pv[kg];
            }
            __asm__ volatile("" ::: "memory");

            // PV: 16 MFMA. Pl read: row=row16, chunk=c*4+quad, phys=chunk^(row16&7)
            __builtin_amdgcn_s_setprio(1);
#pragma unroll
            for (int c = 0; c < 2; c++) {
                bf16x8 pf = *(const bf16x8*)(PlB + wid * 2048 + row16 * 128
                                             + ((((c << 2) + quad) ^ (row16 & 7)) << 4));
#pragma unroll
                for (int dt = 0; dt < 8; dt++) {
                    int vrow = dt * 16 + row16;
                    int phys = (c * 4 + quad) ^ (row16 & 7);
                    bf16x8 vf = *(const bf16x8*)(VsB + cur * 16384 + vrow * 128 + phys * 16);
                    o[dt] = MFMA16(pf, vf, o[dt]);
                }
            }
            __builtin_amdgcn_s_setprio(0);
            __asm__ volatile("" ::: "memory");
            __syncthreads();   // reads of `cur` done; prefetch landed
        }

        // final 16-lane reduction of l per row; write O into qkv's Q slot
#pragma unroll
        for (int r = 0; r < 4; r++) {
            float l = lsum[r];
#pragma unroll
            for (int off = 1; off < 16; off <<= 1)
                l += __shfl_xor(l, off, 64);
            float rl = 1.0f / l;
            int trow = qr0 + quad * 4 + r;
            bf16* dst = qkv + ((size_t)(b * TSEQ + trow)) * NQKV + h * HD;
#pragma unroll
            for (int dt = 0; dt < 8; dt++)
                dst[dt * 16 + row16] = __float2bfloat16(o[dt][r] * rl);
        }
    }
}

// ---------------------------------------------------------------------------
extern "C" void kernel_launch(void* const* d_in, const int* in_sizes, int n_in,
                              void* d_out, int out_size, void* d_ws, size_t ws_size,
                              hipStream_t stream)
{
    // ws (bf16 elems): qkv [4096,3072] 25.2MB | vt 4.2MB | wqkvb [3072,2048]
    // 12.6MB (reused for wprojb after gemm1) | flag | xb [4096,2048] 16.8MB.
    bf16* qkv   = (bf16*)d_ws;
    bf16* vt    = qkv + (size_t)BT * NQKV;
    bf16* wqkvb = vt + (size_t)2 * 4 * HD * TSEQ;
    int* flagp  = (int*)(wqkvb + (size_t)NQKV * CE);
    bf16* xb    = wqkvb + (size_t)NQKV * CE + 16;   // 32B after flag, 16B-aligned

    const size_t need = ((size_t)BT * NQKV + (size_t)2 * 4 * HD * TSEQ
                         + (size_t)NQKV * CE + 16 + (size_t)BT * CE) * sizeof(bf16);
    const bool useXb = ws_size >= need;

    // 0) detect input dtype -> device flag
    detect_dtype<<<1, 256, 0, stream>>>((const unsigned short*)d_in[0], flagp);

    // 1) convert wq/wk/wv to fused bf16 [3072][2048]
    conv_bf16<<<(2048 * 2048 / 8) / 256, 256, 0, stream>>>(d_in[3], wqkvb, flagp);
    conv_bf16<<<(512 * 2048 / 8) / 256, 256, 0, stream>>>(d_in[4], wqkvb + (size_t)2048 * 2048, flagp);
    conv_bf16<<<(512 * 2048 / 8) / 256, 256, 0, stream>>>(d_in[5], wqkvb + (size_t)2560 * 2048, flagp);

    // 2) fused QKV projection
    if (useXb) {
        conv_bf16<<<(BT * CE / 8) / 256, 256, 0, stream>>>(d_in[0], xb, flagp);
        gemmP<8><<<dim3(NQKV / 256, BT / 256), 512, 0, stream>>>(
            xb, wqkvb, qkv, BT, NQKV, CE, CE, 0, flagp);
    } else {
        gemm_bt<<<dim3(NQKV / 128, BT / 128), 256, 0, stream>>>(
            d_in[0], wqkvb, qkv, BT, NQKV, CE, CE, 1, 0, flagp);
    }

    // 3) convert wproj into the same buffer (stream-ordered after gemm1)
    conv_bf16<<<(2048 * 2048 / 8) / 256, 256, 0, stream>>>(d_in[6], wqkvb, flagp);

    // 4) V transpose to [B,KV,D,T] (LDS-tiled, coalesced both sides)
    vtrans<<<256, 256, 0, stream>>>(qkv, vt);

    // 5) RoPE + RMSNorm in place (q scaled by QSCALE)
    rope_rms<<<(BT * 20) / 4, 256, 0, stream>>>(qkv, d_in[1], d_in[2], flagp);

    // 6) balanced GQA-fused flash attention; O overwrites qkv's Q columns
    attn<<<dim3(32, 2 * 4), 512, 0, stream>>>(qkv, vt);

    // 7) output projection: A=qkv cols 0..2047 (bf16, lda=3072)
    if (useXb) {
        gemmP<4><<<dim3(CE / 256, BT / 128), 512, 0, stream>>>(
            qkv, wqkvb, d_out, BT, CE, CE, NQKV, 1, flagp);
    } else {
        gemm_bt<<<dim3(CE / 128, BT / 128), 256, 0, stream>>>(
            qkv, wqkvb, d_out, BT, CE, CE, NQKV, 0, 1, flagp);
    }
}